// Round 9
// baseline (429.590 us; speedup 1.0000x reference)
//
#include <hip/hip_runtime.h>
#include <cfloat>

// VQ forward, MI355X. z[16,256,32,32] f32, emb[8192,256] f32, proj[256,256] f32.
// N = 16384 rows, K = 8192 codes, D = 256.
// d_out (floats): out[4194304] | loss | commitment | codebook_loss | idx_as_float[16384]
//
// R9 = R8 algorithm (two-scan exact-threshold filter + exact rescore; proven, absmax
// 1.9e-6) with the scan kernel rebuilt: A-frags in 128 VGPRs (no zs), rt=4/ct=4 wave
// tile (1 B-read per 4 MFMA), double-buffered es staging (drain hidden), parity-
// rotation swizzle (2-way bank aliasing = free). Scores bitwise identical to R8
// (same zh/eh bits, same d-ascending 8-MFMA chain), so the DLT margin proof carries.
// Filter score is s' = nk - 2*dot (zn dropped: row-constant shift, filter-only).

constexpr int Dd = 256;
constexpr float INV_M = 1.0f / 4194304.0f;
constexpr float DLT = 1e-3f;

typedef unsigned short u16;
typedef unsigned int u32;
typedef __attribute__((ext_vector_type(8))) short short8;   // 8 bf16
typedef __attribute__((ext_vector_type(4))) float f32x4;

#define GLOBAL_AS __attribute__((address_space(1)))
#define LDS_AS    __attribute__((address_space(3)))

__device__ __forceinline__ unsigned monof(float f) {
  unsigned u = __float_as_uint(f);
  return (u & 0x80000000u) ? ~u : (u | 0x80000000u);
}
__device__ __forceinline__ float unmonof(unsigned p) {
  unsigned u = (p & 0x80000000u) ? (p & 0x7FFFFFFFu) : ~p;
  return __uint_as_float(u);
}
__device__ __forceinline__ u16 f2bf(float x) {   // RNE float->bf16 bits
  unsigned u = __float_as_uint(x);
  u += 0x7FFFu + ((u >> 16) & 1u);
  return (u16)(u >> 16);
}

// ---- K1: codebook = emb @ proj^T -> cb[k][d] fp32 + eh bf16[k][d] ----
__global__ __launch_bounds__(256)
void k_codebook(const float* __restrict__ emb, const float* __restrict__ proj,
                float* __restrict__ cb, u16* __restrict__ eh) {
  __shared__ float et[64 * 65];
  __shared__ float pt[64 * 65];
  const int t = threadIdx.x;
  const int tx = t & 15, ty = t >> 4;
  const int kb = blockIdx.x * 64;
  const int db = blockIdx.y * 64;
  float acc[4][4];
#pragma unroll
  for (int u = 0; u < 4; ++u)
#pragma unroll
    for (int v = 0; v < 4; ++v) acc[u][v] = 0.f;

  const int jm = t & 15;
  const int q  = t >> 4;

  for (int jc = 0; jc < Dd; jc += 64) {
    __syncthreads();
#pragma unroll
    for (int i = 0; i < 4; ++i) {
      const int row = q + i * 16;
      const float4 e4 = *(const float4*)(emb  + (size_t)(kb + row) * Dd + jc + jm * 4);
      const float4 p4 = *(const float4*)(proj + (size_t)(db + row) * Dd + jc + jm * 4);
      et[(jm*4 + 0) * 65 + row] = e4.x;
      et[(jm*4 + 1) * 65 + row] = e4.y;
      et[(jm*4 + 2) * 65 + row] = e4.z;
      et[(jm*4 + 3) * 65 + row] = e4.w;
      pt[(jm*4 + 0) * 65 + row] = p4.x;
      pt[(jm*4 + 1) * 65 + row] = p4.y;
      pt[(jm*4 + 2) * 65 + row] = p4.z;
      pt[(jm*4 + 3) * 65 + row] = p4.w;
    }
    __syncthreads();
#pragma unroll 16
    for (int j = 0; j < 64; ++j) {
      float a[4], b[4];
#pragma unroll
      for (int u = 0; u < 4; ++u) a[u] = et[j*65 + ty*4 + u];
#pragma unroll
      for (int v = 0; v < 4; ++v) b[v] = pt[j*65 + tx*4 + v];
#pragma unroll
      for (int u = 0; u < 4; ++u)
#pragma unroll
        for (int v = 0; v < 4; ++v) acc[u][v] = fmaf(a[u], b[v], acc[u][v]);
    }
  }
#pragma unroll
  for (int u = 0; u < 4; ++u) {
    const int k = kb + ty*4 + u;
#pragma unroll
    for (int v = 0; v < 4; ++v) {
      const int d = db + tx*4 + v;
      const float val = acc[u][v];
      cb[(size_t)k * Dd + d] = val;
      eh[(size_t)k * Dd + d] = f2bf(val);
    }
  }
}

// ---- K1b: per-code norms (ascending-d fmaf chain) ----
__global__ __launch_bounds__(256)
void k_norms(const float* __restrict__ cb, float* __restrict__ norms) {
  const int k = blockIdx.x * 256 + threadIdx.x;
  const float* row = cb + (size_t)k * Dd;
  float s = 0.f;
  for (int d = 0; d < Dd; d += 4) {
    const float4 v = *(const float4*)(row + d);
    s = fmaf(v.x, v.x, s);
    s = fmaf(v.y, v.y, s);
    s = fmaf(v.z, v.z, s);
    s = fmaf(v.w, v.w, s);
  }
  norms[k] = s;
}

// ---- K1c: transpose z -> zh bf16 [n][d] + znorm ----
__global__ __launch_bounds__(256)
void k_prep_z(const float* __restrict__ z, u16* __restrict__ zh,
              float* __restrict__ znorm) {
  __shared__ float tile[256 * 33];
  const int t = threadIdx.x;
  const int blk = blockIdx.x;            // b*32 + h
  const int w = t & 31, rg = t >> 5;
  const size_t zbase = (size_t)(blk >> 5) * 262144 + (size_t)(blk & 31) * 32 + w;
#pragma unroll 8
  for (int i = 0; i < 32; ++i) {
    const int d = rg * 32 + i;
    tile[d * 33 + w] = z[zbase + (size_t)d * 1024];
  }
  __syncthreads();
  if (t < 32) {
    float s = 0.f;
    for (int d = 0; d < Dd; ++d) {
      const float v = tile[d * 33 + t];
      s = fmaf(v, v, s);
    }
    znorm[blk * 32 + t] = s;
  }
  const int nl = t >> 3, seg = t & 7;
  const size_t obase = (size_t)(blk * 32 + nl) * Dd + seg * 32;
#pragma unroll
  for (int j = 0; j < 4; ++j) {
    u16 hb[8];
#pragma unroll
    for (int e = 0; e < 8; ++e)
      hb[e] = f2bf(tile[(seg * 32 + j * 8 + e) * 33 + nl]);
    *(uint4*)(zh + obase + j * 8) = *(const uint4*)hb;
  }
}

// ---- es staging: 256 cols x 32 d (16 KB) per phase, 4 instrs/wave ----
// es[col][slot] (slot=0..3, 16B chunks) holds global d-chunk (slot-(col>>1))&3.
// Read with slot=(qd+(col>>1))&3 -> addr16B = 4*col + rot: all 8 bank-groups
// hit 2x per 16 lanes -> 2-way aliasing = free (m136).
__device__ __forceinline__ void stage_es(const u16* __restrict__ eh, u16* esb,
                                         int KB, int d0, int wv, int lane) {
#pragma unroll
  for (int i = 0; i < 4; ++i) {
    const int cb0 = (wv * 4 + i) * 16;          // 16 cols per instr
    const int col_l = cb0 + (lane >> 2);
    const int cgl = ((lane & 3) - ((col_l >> 1) & 3)) & 3;
    const u16* gp = eh + (size_t)(KB + col_l) * 256 + d0 + cgl * 8;
    __builtin_amdgcn_global_load_lds((const GLOBAL_AS void*)gp,
                                     (LDS_AS void*)(esb + cb0 * 32), 16, 0, 0);
  }
}

// ---- K2: MFMA scan. Block 64 rows x 1024 cols; 4 waves x (64 rows x 64 cols) ----
// A-frags (z rows) in registers for all 256 d (loaded once).  B via dbuf es.
template <bool EMIT>
__global__ __launch_bounds__(256, 2)
void k_scan(const u16* __restrict__ zh, const u16* __restrict__ eh,
            const float* __restrict__ norms,
            u32* __restrict__ rowminG, const float* __restrict__ rowThr,
            u32* __restrict__ rowcnt, u16* __restrict__ slots) {
  __shared__ u16 es[2][8192];   // 2 x 16 KB
  const int t    = threadIdx.x;
  const int lane = t & 63;
  const int ml   = lane & 15;
  const int qd   = lane >> 4;
  const int wv   = __builtin_amdgcn_readfirstlane(t >> 6);
  const int bid  = blockIdx.x;
  const int kb   = (bid & 7) * 1024;     // XCD-local eh slice
  const int nb   = (bid >> 3) * 64;

  // A: 4 row-tiles x 8 d-chunks, 128 VGPRs, loaded once
  short8 A[4][8];
#pragma unroll
  for (int rt = 0; rt < 4; ++rt)
#pragma unroll
    for (int dh = 0; dh < 8; ++dh)
      A[rt][dh] = *(const short8*)(zh + (size_t)(nb + rt * 16 + ml) * 256
                                      + dh * 32 + qd * 8);

  float thr[4][4];
  float mv[4][4];
#pragma unroll
  for (int rt = 0; rt < 4; ++rt) {
    if (EMIT) {
      const f32x4 t4 = *(const f32x4*)(rowThr + nb + rt * 16 + qd * 4);
#pragma unroll
      for (int r = 0; r < 4; ++r) thr[rt][r] = t4[r];
    } else {
#pragma unroll
      for (int r = 0; r < 4; ++r) mv[rt][r] = FLT_MAX;
    }
  }

  stage_es(eh, es[0], kb, 0, wv, lane);
  __syncthreads();

#pragma unroll 1
  for (int kt = 0; kt < 4; ++kt) {
    f32x4 acc[4][4];
#pragma unroll
    for (int rt = 0; rt < 4; ++rt)
#pragma unroll
      for (int ct = 0; ct < 4; ++ct) acc[rt][ct] = (f32x4)0.f;

#pragma unroll
    for (int dh = 0; dh < 8; ++dh) {
      const int p = kt * 8 + dh;
      if (p < 31)
        stage_es(eh, es[(p + 1) & 1], kb + ((p + 1) >> 3) * 256,
                 ((p + 1) & 7) * 32, wv, lane);
      const u16* esb = es[p & 1];
      short8 B[4];
#pragma unroll
      for (int ct = 0; ct < 4; ++ct) {
        const int col_l = wv * 64 + ct * 16 + ml;
        const int slot = (qd + ((col_l >> 1) & 3)) & 3;
        B[ct] = *(const short8*)(esb + col_l * 32 + slot * 8);
      }
#pragma unroll
      for (int ct = 0; ct < 4; ++ct)
#pragma unroll
        for (int rt = 0; rt < 4; ++rt)
          acc[rt][ct] = __builtin_amdgcn_mfma_f32_16x16x32_bf16(
              A[rt][dh], B[ct], acc[rt][ct], 0, 0, 0);
      __syncthreads();
    }

    // fold kt: filter score s' = nk - 2*dot (row-constant zn dropped)
    const int KB = kb + kt * 256;
#pragma unroll
    for (int ct = 0; ct < 4; ++ct) {
      const int k = KB + wv * 64 + ct * 16 + ml;
      const float nk = norms[k];
#pragma unroll
      for (int rt = 0; rt < 4; ++rt)
#pragma unroll
        for (int r = 0; r < 4; ++r) {
          const float sc = fmaf(-2.0f, acc[rt][ct][r], nk);
          if (!EMIT) {
            mv[rt][r] = fminf(mv[rt][r], sc);
          } else if (sc <= thr[rt][r]) {
            const int n = nb + rt * 16 + qd * 4 + r;
            const u32 pos = atomicAdd(&rowcnt[n], 1u);
            if (pos < 32u) slots[n * 32 + pos] = (u16)k;
          }
        }
    }
  }

  if (!EMIT) {
#pragma unroll
    for (int rt = 0; rt < 4; ++rt)
#pragma unroll
      for (int r = 0; r < 4; ++r) {
        float m = mv[rt][r];
#pragma unroll
        for (int s = 1; s < 16; s <<= 1) m = fminf(m, __shfl_xor(m, s, 64));
        if (ml == 0)
          atomicMin(&rowminG[nb + rt * 16 + qd * 4 + r], monof(m));
      }
  }
}

// ---- K2b: threshold (in s'-space) ----
__global__ __launch_bounds__(256)
void k_thresh(const u32* __restrict__ rowminG, float* __restrict__ rowThr) {
  const int n = blockIdx.x * 256 + threadIdx.x;
  rowThr[n] = unmonof(rowminG[n]) + DLT;
}

// ---- K2c: exact rescore of slot candidates (bit-identical chain to R2-R5) ----
__global__ __launch_bounds__(256)
void k_rescore(const float* __restrict__ z, const float* __restrict__ cb,
               const float* __restrict__ norms, const float* __restrict__ znorm,
               const u32* __restrict__ rowcnt, const u16* __restrict__ slots,
               unsigned long long* __restrict__ packed) {
  __shared__ float ztl[32 * 261];
  const int t = threadIdx.x;
  const int blk = blockIdx.x;          // b*32 + h
  const int w = t & 31, dg = t >> 5;
  const size_t zbase = (size_t)(blk >> 5) * 262144 + (size_t)(blk & 31) * 32;
#pragma unroll 8
  for (int i = 0; i < 32; ++i) {
    const int d = dg * 32 + i;
    ztl[w * 261 + d] = z[zbase + (size_t)d * 1024 + w];
  }
  __syncthreads();

  const int lane = t & 63;
  const int wv = t >> 6;
#pragma unroll 1
  for (int i = 0; i < 8; ++i) {
    const int rl = wv * 8 + i;
    const int n = blk * 32 + rl;
    const u32 cnt = min(rowcnt[n], 32u);
    const float znr = znorm[n];
    unsigned long long best = 0xFFFFFFFFFFFFFFFFull;
    for (u32 c = 0; c < cnt; ++c) {
      const int k = (int)slots[n * 32 + c];
      const float4 c4 = *(const float4*)(cb + (size_t)k * Dd + lane * 4);
      const float* zp = ztl + rl * 261 + lane * 4;
      float p = 0.f;
      p = fmaf(zp[0], c4.x, p);
      p = fmaf(zp[1], c4.y, p);
      p = fmaf(zp[2], c4.z, p);
      p = fmaf(zp[3], c4.w, p);
#pragma unroll
      for (int s = 1; s < 64; s <<= 1) p += __shfl_xor(p, s, 64);
      const float sc = (znr + norms[k]) - 2.0f * p;   // quantized fold
      const unsigned long long pk =
          ((unsigned long long)monof(sc) << 32) | (unsigned)k;
      if (pk < best) best = pk;                        // ties -> min k
    }
    if (lane == 0 && cnt > 0) packed[n] = best;
  }
}

// ---- K3: gather codes, write out (NCHW), idx floats, reduce SSE ----
__global__ __launch_bounds__(256)
void k_output(const float* __restrict__ z, const float* __restrict__ cb,
              const unsigned long long* __restrict__ packed,
              float* __restrict__ out, float* __restrict__ idxf,
              float* __restrict__ ssum) {
  __shared__ float zqT[256 * 33];
  __shared__ float part[4];
  const int t = threadIdx.x;
  const int blk = blockIdx.x;       // = b*32 + h
  const int nbase = blk * 32;

  {
    const int nl = t >> 3, m = t & 7;
    const int idx = (int)(packed[nbase + nl] & 0xFFFFFFFFull);
    const float* row = cb + (size_t)idx * Dd;
#pragma unroll
    for (int i = 0; i < 8; ++i) {
      const int d0 = m * 4 + i * 32;
      const float4 v = *(const float4*)(row + d0);
      zqT[(d0 + 0) * 33 + nl] = v.x;
      zqT[(d0 + 1) * 33 + nl] = v.y;
      zqT[(d0 + 2) * 33 + nl] = v.z;
      zqT[(d0 + 3) * 33 + nl] = v.w;
    }
    if (t < 32)
      idxf[nbase + t] = (float)(unsigned)(packed[nbase + t] & 0xFFFFFFFFull);
  }
  __syncthreads();

  const int w = t & 31, cg = t >> 5;
  const size_t base = (size_t)(blk >> 5) * 262144 + (size_t)(blk & 31) * 32 + w;
  float local = 0.f;
#pragma unroll
  for (int cc = 0; cc < 32; ++cc) {
    const int c = cg * 32 + cc;
    const float q  = zqT[c * 33 + w];
    const float zv = z[base + (size_t)c * 1024];
    out[base + (size_t)c * 1024] = q;
    const float dd = q - zv;
    local = fmaf(dd, dd, local);
  }
  float v = local;
#pragma unroll
  for (int m = 1; m < 64; m <<= 1) v += __shfl_xor(v, m, 64);
  if ((t & 63) == 0) part[t >> 6] = v;
  __syncthreads();
  if (t == 0) atomicAdd(ssum, part[0] + part[1] + part[2] + part[3]);
}

// ---- K4: finalize scalars ----
__global__ void k_final(const float* __restrict__ ssum, float* __restrict__ scal) {
  const float m = *ssum * INV_M;
  scal[0] = 1.25f * m;   // loss
  scal[1] = 0.25f * m;   // commitment_loss
  scal[2] = m;           // codebook_loss
}

extern "C" void kernel_launch(void* const* d_in, const int* in_sizes, int n_in,
                              void* d_out, int out_size, void* d_ws, size_t ws_size,
                              hipStream_t stream) {
  const float* z    = (const float*)d_in[0];
  const float* emb  = (const float*)d_in[1];
  const float* proj = (const float*)d_in[2];

  float* out  = (float*)d_out;
  float* scal = out + 4194304;
  float* idxf = out + 4194307;

  // ws (~22 MB): cb | norms | packed | znorm | zh | eh | rowminG | rowThr | rowcnt | slots | ssum
  float* cb    = (float*)d_ws;                          // 8 MB
  float* norms = cb + 2097152;                          // 32 KB
  unsigned long long* packed =
      (unsigned long long*)(norms + 8192);              // 128 KB
  float* znorm = (float*)(packed + 16384);              // 64 KB
  u16* zh = (u16*)(znorm + 16384);                      // 8.4 MB
  u16* eh = zh + 4194304;                               // 4.2 MB
  u32* rowminG = (u32*)(eh + 2097152);                  // 64 KB
  float* rowThr = (float*)(rowminG + 16384);            // 64 KB
  u32* rowcnt = (u32*)(rowThr + 16384);                 // 64 KB
  u16* slots = (u16*)(rowcnt + 16384);                  // 1 MB
  float* ssum = (float*)(slots + 16384 * 32);           // 4 B

  hipMemsetAsync(rowminG, 0xFF, 16384 * sizeof(u32), stream);
  hipMemsetAsync(rowcnt, 0, 16384 * sizeof(u32), stream);
  hipMemsetAsync(packed, 0xFF, 16384 * sizeof(unsigned long long), stream);
  hipMemsetAsync(ssum, 0, sizeof(float), stream);

  k_codebook<<<dim3(128, 4), 256, 0, stream>>>(emb, proj, cb, eh);
  k_norms   <<<32, 256, 0, stream>>>(cb, norms);
  k_prep_z  <<<512, 256, 0, stream>>>(z, zh, znorm);
  k_scan<false><<<2048, 256, 0, stream>>>(zh, eh, norms,
                                          rowminG, rowThr, rowcnt, slots);
  k_thresh  <<<64, 256, 0, stream>>>(rowminG, rowThr);
  k_scan<true> <<<2048, 256, 0, stream>>>(zh, eh, norms,
                                          rowminG, rowThr, rowcnt, slots);
  k_rescore <<<512, 256, 0, stream>>>(z, cb, norms, znorm, rowcnt, slots, packed);
  k_output  <<<512, 256, 0, stream>>>(z, cb, packed, out, idxf, ssum);
  k_final   <<<1, 1, 0, stream>>>(ssum, scal);

  (void)in_sizes; (void)n_in; (void)out_size; (void)ws_size;
}